// Round 1
// baseline (710.023 us; speedup 1.0000x reference)
//
#include <hip/hip_runtime.h>

typedef __attribute__((ext_vector_type(8))) short short8;
typedef __attribute__((ext_vector_type(4))) float f32x4;

#define MFMA16(a, b, c) __builtin_amdgcn_mfma_f32_16x16x32_bf16(a, b, c, 0, 0, 0)

__device__ __forceinline__ unsigned short f2bf(float f) {
  unsigned int u = __float_as_uint(f);
  u += 0x7fffu + ((u >> 16) & 1u);
  return (unsigned short)(u >> 16);
}

// ---------------- conversion kernels ----------------
__global__ __launch_bounds__(256) void cvt_f32_bf16_k(const float* __restrict__ in,
                                                      unsigned short* __restrict__ out,
                                                      int n4) {
  int i = blockIdx.x * 256 + threadIdx.x;
  if (i < n4) {
    float4 v = reinterpret_cast<const float4*>(in)[i];
    ushort4 o;
    o.x = f2bf(v.x); o.y = f2bf(v.y); o.z = f2bf(v.z); o.w = f2bf(v.w);
    reinterpret_cast<ushort4*>(out)[i] = o;
  }
}

// W [1024][N] fp32 -> Wt [N][1024] bf16
__global__ __launch_bounds__(256) void cvt_transpose_k(const float* __restrict__ W,
                                                       unsigned short* __restrict__ Wt,
                                                       int N) {
  int idx = blockIdx.x * 256 + threadIdx.x;  // = n*1024 + k
  int n = idx >> 10, k = idx & 1023;
  Wt[idx] = f2bf(W[(size_t)k * N + n]);
}

// ---------------- GEMM: C = A @ Bt^T + bias ----------------
// A [M,K] bf16 row-major, Bt [N,K] bf16 row-major (i.e., B transposed)
// MODE 0: scatter QKV epilogue (N=3072).  MODE 1: fp32 out [M,N].
template <int MODE>
__global__ __launch_bounds__(256) void gemm_bt(const unsigned short* __restrict__ A,
                                               const unsigned short* __restrict__ Bt,
                                               const float* __restrict__ bias,
                                               float* __restrict__ outF,
                                               unsigned short* __restrict__ q_ws,
                                               unsigned short* __restrict__ k_ws,
                                               unsigned short* __restrict__ vt_ws,
                                               int M, int N, int K) {
  __shared__ unsigned short As[128 * 32];
  __shared__ unsigned short Bs[128 * 32];

  const int tid = threadIdx.x;
  const int wave = tid >> 6, lane = tid & 63;
  const int quad = lane >> 4, l15 = lane & 15;
  const int m0 = blockIdx.x * 128, n0 = blockIdx.y * 128;
  const int wm = (wave & 1) * 64, wn = (wave >> 1) * 64;

  const f32x4 zf = {0.f, 0.f, 0.f, 0.f};
  f32x4 acc[4][4];
#pragma unroll
  for (int i = 0; i < 4; ++i)
#pragma unroll
    for (int j = 0; j < 4; ++j) acc[i][j] = zf;

  const int ar = tid >> 2;        // staging row 0..63 (+64 on 2nd iter)
  const int ac = (tid & 3) * 8;   // staging col chunk (8 bf16 = 16B)

  for (int kt = 0; kt < K; kt += 32) {
    __syncthreads();
#pragma unroll
    for (int i = 0; i < 2; ++i) {
      int r = ar + i * 64;
      *reinterpret_cast<uint4*>(&As[r * 32 + ac]) =
          *reinterpret_cast<const uint4*>(&A[(size_t)(m0 + r) * K + kt + ac]);
      *reinterpret_cast<uint4*>(&Bs[r * 32 + ac]) =
          *reinterpret_cast<const uint4*>(&Bt[(size_t)(n0 + r) * K + kt + ac]);
    }
    __syncthreads();

    short8 af[4], bg[4];
#pragma unroll
    for (int i = 0; i < 4; ++i)
      af[i] = *reinterpret_cast<const short8*>(&As[(wm + i * 16 + l15) * 32 + quad * 8]);
#pragma unroll
    for (int j = 0; j < 4; ++j)
      bg[j] = *reinterpret_cast<const short8*>(&Bs[(wn + j * 16 + l15) * 32 + quad * 8]);
#pragma unroll
    for (int i = 0; i < 4; ++i)
#pragma unroll
      for (int j = 0; j < 4; ++j) acc[i][j] = MFMA16(af[i], bg[j], acc[i][j]);
  }

  // epilogue
#pragma unroll
  for (int i = 0; i < 4; ++i) {
#pragma unroll
    for (int j = 0; j < 4; ++j) {
      const int n = n0 + wn + j * 16 + l15;
      const float bv = bias[n];
#pragma unroll
      for (int r = 0; r < 4; ++r) {
        const int m = m0 + wm + i * 16 + quad * 4 + r;
        const float v = acc[i][j][r] + bv;
        if (MODE == 1) {
          outF[(size_t)m * N + n] = v;
        } else {
          const int b = m >> 11, t = m & 2047;
          const unsigned short bw = f2bf(v);
          if (n < 1024) {
            int h = n >> 6, d = n & 63;
            q_ws[(((size_t)(b * 16 + h)) * 2048 + t) * 64 + d] = bw;
          } else if (n < 2048) {
            int n2 = n - 1024, h = n2 >> 6, d = n2 & 63;
            k_ws[(((size_t)(b * 16 + h)) * 2048 + t) * 64 + d] = bw;
          } else {
            int n2 = n - 2048, h = n2 >> 6, d = n2 & 63;
            vt_ws[(((size_t)(b * 16 + h)) * 64 + d) * 2048 + t] = bw;
          }
        }
      }
    }
  }
}

// ---------------- flash attention ----------------
// Q,K: [B*H, T, 64] bf16; Vt: [B*H, 64, T] bf16; att: [B*T, 1024] bf16
__global__ __launch_bounds__(256) void attn_k(const unsigned short* __restrict__ q_ws,
                                              const unsigned short* __restrict__ k_ws,
                                              const unsigned short* __restrict__ vt_ws,
                                              unsigned short* __restrict__ att_ws) {
  const int T = 2048;
  const int qt = blockIdx.x;  // 0..31 (64-query tile)
  const int bh = blockIdx.y;  // 0..63
  const int wave = threadIdx.x >> 6, lane = threadIdx.x & 63;
  const int quad = lane >> 4, l15 = lane & 15;

  const unsigned short* Qh = q_ws + (size_t)bh * T * 64;
  const unsigned short* Kh = k_ws + (size_t)bh * T * 64;
  const unsigned short* Vh = vt_ws + (size_t)bh * 64 * T;

  __shared__ unsigned short plds_all[4][16 * 72];  // pad 72: 16B-aligned rows, low conflicts
  unsigned short* plds = plds_all[wave];

  const int qrowA = qt * 64 + wave * 16 + l15;  // A-frag m-index
  const short8 qa0 = *reinterpret_cast<const short8*>(&Qh[qrowA * 64 + quad * 8]);
  const short8 qa1 = *reinterpret_cast<const short8*>(&Qh[qrowA * 64 + 32 + quad * 8]);

  const f32x4 zf = {0.f, 0.f, 0.f, 0.f};
  f32x4 o[4];
#pragma unroll
  for (int n = 0; n < 4; ++n) o[n] = zf;
  float m_i[4] = {-1e30f, -1e30f, -1e30f, -1e30f};
  float l_i[4] = {0.f, 0.f, 0.f, 0.f};
  const float kSc = 0.125f * 1.44269504088896f;  // log2(e)/sqrt(64)

  for (int kt = 0; kt <= qt; ++kt) {
    const int kb = kt * 64;
    f32x4 s[4];
#pragma unroll
    for (int c = 0; c < 4; ++c) {
      const unsigned short* kp = &Kh[(size_t)(kb + c * 16 + l15) * 64 + quad * 8];
      short8 k0 = *reinterpret_cast<const short8*>(kp);
      short8 k1 = *reinterpret_cast<const short8*>(kp + 32);
      f32x4 t0 = MFMA16(qa0, k0, zf);
      s[c] = MFMA16(qa1, k1, t0);
    }
    const bool diag = (kt == qt);
#pragma unroll
    for (int c = 0; c < 4; ++c)
#pragma unroll
      for (int r = 0; r < 4; ++r) {
        float v = s[c][r] * kSc;
        if (diag && (kb + c * 16 + l15) > (qt * 64 + wave * 16 + quad * 4 + r)) v = -1e30f;
        s[c][r] = v;
      }
    // row max across 4 col-tiles then across the 16 lanes holding the row
    float mt[4];
#pragma unroll
    for (int r = 0; r < 4; ++r)
      mt[r] = fmaxf(fmaxf(s[0][r], s[1][r]), fmaxf(s[2][r], s[3][r]));
#pragma unroll
    for (int d = 1; d < 16; d <<= 1)
#pragma unroll
      for (int r = 0; r < 4; ++r) mt[r] = fmaxf(mt[r], __shfl_xor(mt[r], d));
    float alpha[4];
#pragma unroll
    for (int r = 0; r < 4; ++r) {
      float mn = fmaxf(m_i[r], mt[r]);
      alpha[r] = exp2f(m_i[r] - mn);
      m_i[r] = mn;
    }
    float rs[4] = {0.f, 0.f, 0.f, 0.f};
#pragma unroll
    for (int c = 0; c < 4; ++c)
#pragma unroll
      for (int r = 0; r < 4; ++r) {
        float p = exp2f(s[c][r] - m_i[r]);
        rs[r] += p;
        plds[(quad * 4 + r) * 72 + c * 16 + l15] = f2bf(p);
      }
#pragma unroll
    for (int d = 1; d < 16; d <<= 1)
#pragma unroll
      for (int r = 0; r < 4; ++r) rs[r] += __shfl_xor(rs[r], d);
#pragma unroll
    for (int r = 0; r < 4; ++r) l_i[r] = l_i[r] * alpha[r] + rs[r];
#pragma unroll
    for (int n = 0; n < 4; ++n)
#pragma unroll
      for (int r = 0; r < 4; ++r) o[n][r] *= alpha[r];

    __syncthreads();  // P writes -> A-frag reads (uniform loop count per block)
#pragma unroll
    for (int ks = 0; ks < 2; ++ks) {
      short8 pa = *reinterpret_cast<const short8*>(&plds[l15 * 72 + ks * 32 + quad * 8]);
#pragma unroll
      for (int n = 0; n < 4; ++n) {
        short8 vb = *reinterpret_cast<const short8*>(
            &Vh[(size_t)(n * 16 + l15) * T + kb + ks * 32 + quad * 8]);
        o[n] = MFMA16(pa, vb, o[n]);
      }
    }
    __syncthreads();  // A-frag reads done before next iter's P writes
  }

  const int b = bh >> 4, h = bh & 15;
#pragma unroll
  for (int n = 0; n < 4; ++n)
#pragma unroll
    for (int r = 0; r < 4; ++r) {
      const int q = qt * 64 + wave * 16 + quad * 4 + r;
      att_ws[(size_t)(b * 2048 + q) * 1024 + h * 64 + n * 16 + l15] =
          f2bf(o[n][r] / l_i[r]);
    }
}

// ---------------- launch ----------------
extern "C" void kernel_launch(void* const* d_in, const int* in_sizes, int n_in,
                              void* d_out, int out_size, void* d_ws, size_t ws_size,
                              hipStream_t stream) {
  (void)in_sizes; (void)n_in; (void)out_size; (void)ws_size;
  const float* x     = (const float*)d_in[0];
  const float* W_qkv = (const float*)d_in[1];
  const float* b_qkv = (const float*)d_in[2];
  const float* W_out = (const float*)d_in[3];
  const float* b_out = (const float*)d_in[4];
  float* out = (float*)d_out;

  char* ws = (char*)d_ws;
  unsigned short* xb    = (unsigned short*)(ws);                       // 16 MB
  unsigned short* wqkvT = (unsigned short*)(ws + 16777216);            // 6 MB
  unsigned short* woutT = (unsigned short*)(ws + 23068672);            // 2 MB
  unsigned short* q_ws  = (unsigned short*)(ws + 25165824);            // 16 MB
  unsigned short* k_ws  = (unsigned short*)(ws + 41943040);            // 16 MB
  unsigned short* vt_ws = (unsigned short*)(ws + 58720256);            // 16 MB
  unsigned short* attb  = (unsigned short*)(ws + 75497472);            // 16 MB

  cvt_f32_bf16_k<<<8192, 256, 0, stream>>>(x, xb, 2097152);         // 8192*1024/4
  cvt_transpose_k<<<12288, 256, 0, stream>>>(W_qkv, wqkvT, 3072);
  cvt_transpose_k<<<4096, 256, 0, stream>>>(W_out, woutT, 1024);

  dim3 g1(64, 24);
  gemm_bt<0><<<g1, 256, 0, stream>>>(xb, wqkvT, b_qkv, nullptr, q_ws, k_ws, vt_ws,
                                     8192, 3072, 1024);
  dim3 ga(32, 64);
  attn_k<<<ga, 256, 0, stream>>>(q_ws, k_ws, vt_ws, attb);

  dim3 g2(64, 8);
  gemm_bt<1><<<g2, 256, 0, stream>>>(attb, woutT, b_out, out, nullptr, nullptr, nullptr,
                                     8192, 1024, 1024);
}

// Round 2
// 457.484 us; speedup vs baseline: 1.5520x; 1.5520x over previous
//
#include <hip/hip_runtime.h>

typedef __attribute__((ext_vector_type(8))) short short8;
typedef __attribute__((ext_vector_type(4))) float f32x4;

#define MFMA16(a, b, c) __builtin_amdgcn_mfma_f32_16x16x32_bf16(a, b, c, 0, 0, 0)

__device__ __forceinline__ unsigned short f2bf(float f) {
  unsigned int u = __float_as_uint(f);
  u += 0x7fffu + ((u >> 16) & 1u);
  return (unsigned short)(u >> 16);
}

// ---------------- conversion kernels ----------------
__global__ __launch_bounds__(256) void cvt_f32_bf16_k(const float* __restrict__ in,
                                                      unsigned short* __restrict__ out,
                                                      int n4) {
  int i = blockIdx.x * 256 + threadIdx.x;
  if (i < n4) {
    float4 v = reinterpret_cast<const float4*>(in)[i];
    ushort4 o;
    o.x = f2bf(v.x); o.y = f2bf(v.y); o.z = f2bf(v.z); o.w = f2bf(v.w);
    reinterpret_cast<ushort4*>(out)[i] = o;
  }
}

// W [1024][N] fp32 -> Wt [N][1024] bf16
__global__ __launch_bounds__(256) void cvt_transpose_k(const float* __restrict__ W,
                                                       unsigned short* __restrict__ Wt,
                                                       int N) {
  int idx = blockIdx.x * 256 + threadIdx.x;  // = n*1024 + k
  int n = idx >> 10, k = idx & 1023;
  Wt[idx] = f2bf(W[(size_t)k * N + n]);
}

// ---------------- GEMM: C = A @ Bt^T + bias ----------------
template <int MODE>
__global__ __launch_bounds__(256) void gemm_bt(const unsigned short* __restrict__ A,
                                               const unsigned short* __restrict__ Bt,
                                               const float* __restrict__ bias,
                                               float* __restrict__ outF,
                                               unsigned short* __restrict__ q_ws,
                                               unsigned short* __restrict__ k_ws,
                                               unsigned short* __restrict__ vt_ws,
                                               int M, int N, int K) {
  __shared__ unsigned short As[128 * 32];
  __shared__ unsigned short Bs[128 * 32];

  const int tid = threadIdx.x;
  const int wave = tid >> 6, lane = tid & 63;
  const int quad = lane >> 4, l15 = lane & 15;
  const int m0 = blockIdx.x * 128, n0 = blockIdx.y * 128;
  const int wm = (wave & 1) * 64, wn = (wave >> 1) * 64;

  const f32x4 zf = {0.f, 0.f, 0.f, 0.f};
  f32x4 acc[4][4];
#pragma unroll
  for (int i = 0; i < 4; ++i)
#pragma unroll
    for (int j = 0; j < 4; ++j) acc[i][j] = zf;

  const int ar = tid >> 2;
  const int ac = (tid & 3) * 8;

  for (int kt = 0; kt < K; kt += 32) {
    __syncthreads();
#pragma unroll
    for (int i = 0; i < 2; ++i) {
      int r = ar + i * 64;
      *reinterpret_cast<uint4*>(&As[r * 32 + ac]) =
          *reinterpret_cast<const uint4*>(&A[(size_t)(m0 + r) * K + kt + ac]);
      *reinterpret_cast<uint4*>(&Bs[r * 32 + ac]) =
          *reinterpret_cast<const uint4*>(&Bt[(size_t)(n0 + r) * K + kt + ac]);
    }
    __syncthreads();

    short8 af[4], bg[4];
#pragma unroll
    for (int i = 0; i < 4; ++i)
      af[i] = *reinterpret_cast<const short8*>(&As[(wm + i * 16 + l15) * 32 + quad * 8]);
#pragma unroll
    for (int j = 0; j < 4; ++j)
      bg[j] = *reinterpret_cast<const short8*>(&Bs[(wn + j * 16 + l15) * 32 + quad * 8]);
#pragma unroll
    for (int i = 0; i < 4; ++i)
#pragma unroll
      for (int j = 0; j < 4; ++j) acc[i][j] = MFMA16(af[i], bg[j], acc[i][j]);
  }

#pragma unroll
  for (int i = 0; i < 4; ++i) {
#pragma unroll
    for (int j = 0; j < 4; ++j) {
      const int n = n0 + wn + j * 16 + l15;
      const float bv = bias[n];
#pragma unroll
      for (int r = 0; r < 4; ++r) {
        const int m = m0 + wm + i * 16 + quad * 4 + r;
        const float v = acc[i][j][r] + bv;
        if (MODE == 1) {
          outF[(size_t)m * N + n] = v;
        } else {
          const int b = m >> 11, t = m & 2047;
          const unsigned short bw = f2bf(v);
          if (n < 1024) {
            int h = n >> 6, d = n & 63;
            q_ws[(((size_t)(b * 16 + h)) * 2048 + t) * 64 + d] = bw;
          } else if (n < 2048) {
            int n2 = n - 1024, h = n2 >> 6, d = n2 & 63;
            k_ws[(((size_t)(b * 16 + h)) * 2048 + t) * 64 + d] = bw;
          } else {
            int n2 = n - 2048, h = n2 >> 6, d = n2 & 63;
            vt_ws[(((size_t)(b * 16 + h)) * 64 + d) * 2048 + t] = bw;
          }
        }
      }
    }
  }
}

// ---------------- flash attention, S^T orientation, barrier-free ----------------
// Q,K: [B*H, T, 64] bf16; Vt: [B*H, 64, T] bf16; att: [B*T, 1024] bf16
// Each wave owns a 16-query tile; block pairs q-group p with 31-p => 33 iters/wave.
__global__ __launch_bounds__(256) void attn_k(const unsigned short* __restrict__ q_ws,
                                              const unsigned short* __restrict__ k_ws,
                                              const unsigned short* __restrict__ vt_ws,
                                              unsigned short* __restrict__ att_ws) {
  const int T = 2048;
  const int p = blockIdx.x;   // 0..15
  const int bh = blockIdx.y;  // 0..63
  const int wave = threadIdx.x >> 6, lane = threadIdx.x & 63;
  const int quad = lane >> 4, l15 = lane & 15;

  const unsigned short* Qh = q_ws + (size_t)bh * T * 64;
  const unsigned short* Kh = k_ws + (size_t)bh * T * 64;
  const unsigned short* Vh = vt_ws + (size_t)bh * 64 * T;
  const int b = bh >> 4, h = bh & 15;

  // wave-private P^T scratch: [16 q][72 elem] (stride 144B: 16B-aligned reads,
  // 2-way-max write conflicts which are free)
  __shared__ unsigned short plds_all[4][16 * 72];
  unsigned short* plds = plds_all[wave];

  const f32x4 zf = {0.f, 0.f, 0.f, 0.f};
  const float kSc = 0.125f * 1.44269504088896f;  // log2(e)/sqrt(64)

  for (int half = 0; half < 2; ++half) {
    const int qt = (half == 0) ? p : 31 - p;   // 64-query group
    const int qi = qt * 4 + wave;              // this wave's 16-query tile
    const int q0 = qi * 16;
    const int nk = qt + 1;                     // 64-key tiles needed
    const int myq = q0 + l15;                  // this lane's query (column)

    // Q as B-operand: B[n=q][k=dim]
    const short8 qb0 = *reinterpret_cast<const short8*>(&Qh[(size_t)(q0 + l15) * 64 + quad * 8]);
    const short8 qb1 = *reinterpret_cast<const short8*>(&Qh[(size_t)(q0 + l15) * 64 + 32 + quad * 8]);

    f32x4 o[4];
#pragma unroll
    for (int n = 0; n < 4; ++n) o[n] = zf;
    float m_i = -1e30f, l_i = 0.f;

    for (int kt = 0; kt < nk; ++kt) {
      const int kb = kt * 64;
      // S^T = K·Q^T : lane holds col q=l15, rows key = kb + c*16 + quad*4 + r
      f32x4 s[4];
#pragma unroll
      for (int c = 0; c < 4; ++c) {
        const unsigned short* kp = &Kh[(size_t)(kb + c * 16 + l15) * 64 + quad * 8];
        short8 k0 = *reinterpret_cast<const short8*>(kp);
        short8 k1 = *reinterpret_cast<const short8*>(kp + 32);
        s[c] = MFMA16(k1, qb1, MFMA16(k0, qb0, zf));
      }
      // scale + causal mask + tile max (in-register over this lane's 16 keys)
      float mt = -1e30f;
#pragma unroll
      for (int c = 0; c < 4; ++c)
#pragma unroll
        for (int r = 0; r < 4; ++r) {
          const int key = kb + c * 16 + quad * 4 + r;
          float v = s[c][r] * kSc;
          v = (key > myq) ? -1e30f : v;
          s[c][r] = v;
          mt = fmaxf(mt, v);
        }
      mt = fmaxf(mt, __shfl_xor(mt, 16));
      mt = fmaxf(mt, __shfl_xor(mt, 32));
      const float mn = fmaxf(m_i, mt);
      const float alpha = exp2f(m_i - mn);
      m_i = mn;

      float rs = 0.f;
#pragma unroll
      for (int c = 0; c < 4; ++c) {
        float p0 = exp2f(s[c][0] - mn);
        float p1 = exp2f(s[c][1] - mn);
        float p2 = exp2f(s[c][2] - mn);
        float p3 = exp2f(s[c][3] - mn);
        rs += (p0 + p1) + (p2 + p3);
        uint2 pk;
        pk.x = (unsigned)f2bf(p0) | ((unsigned)f2bf(p1) << 16);
        pk.y = (unsigned)f2bf(p2) | ((unsigned)f2bf(p3) << 16);
        *reinterpret_cast<uint2*>(&plds[l15 * 72 + c * 16 + quad * 4]) = pk;
      }
      rs += __shfl_xor(rs, 16);
      rs += __shfl_xor(rs, 32);
      l_i = l_i * alpha + rs;
#pragma unroll
      for (int n = 0; n < 4; ++n)
#pragma unroll
        for (int r = 0; r < 4; ++r) o[n][r] *= alpha;

      // wave-private LDS: only need all DS writes complete (lockstep lanes), no barrier
      asm volatile("s_waitcnt lgkmcnt(0)" ::: "memory");

      // O^T += V^T · P^T : A[m=d][k=key] from Vt, B[n=q][k=key] from plds
#pragma unroll
      for (int ks = 0; ks < 2; ++ks) {
        short8 pb = *reinterpret_cast<const short8*>(&plds[l15 * 72 + ks * 32 + quad * 8]);
#pragma unroll
        for (int n = 0; n < 4; ++n) {
          short8 vf = *reinterpret_cast<const short8*>(
              &Vh[(size_t)(n * 16 + l15) * T + kb + ks * 32 + quad * 8]);
          o[n] = MFMA16(vf, pb, o[n]);
        }
      }
      // WAR guard: reads done before next iteration's P writes
      asm volatile("s_waitcnt lgkmcnt(0)" ::: "memory");
    }

    const float inv = 1.f / l_i;
#pragma unroll
    for (int n = 0; n < 4; ++n) {
      uint2 ov;
      ov.x = (unsigned)f2bf(o[n][0] * inv) | ((unsigned)f2bf(o[n][1] * inv) << 16);
      ov.y = (unsigned)f2bf(o[n][2] * inv) | ((unsigned)f2bf(o[n][3] * inv) << 16);
      *reinterpret_cast<uint2*>(
          &att_ws[(size_t)(b * 2048 + q0 + l15) * 1024 + h * 64 + n * 16 + quad * 4]) = ov;
    }
  }
}

// ---------------- launch ----------------
extern "C" void kernel_launch(void* const* d_in, const int* in_sizes, int n_in,
                              void* d_out, int out_size, void* d_ws, size_t ws_size,
                              hipStream_t stream) {
  (void)in_sizes; (void)n_in; (void)out_size; (void)ws_size;
  const float* x     = (const float*)d_in[0];
  const float* W_qkv = (const float*)d_in[1];
  const float* b_qkv = (const float*)d_in[2];
  const float* W_out = (const float*)d_in[3];
  const float* b_out = (const float*)d_in[4];
  float* out = (float*)d_out;

  char* ws = (char*)d_ws;
  unsigned short* xb    = (unsigned short*)(ws);
  unsigned short* wqkvT = (unsigned short*)(ws + 16777216);
  unsigned short* woutT = (unsigned short*)(ws + 23068672);
  unsigned short* q_ws  = (unsigned short*)(ws + 25165824);
  unsigned short* k_ws  = (unsigned short*)(ws + 41943040);
  unsigned short* vt_ws = (unsigned short*)(ws + 58720256);
  unsigned short* attb  = (unsigned short*)(ws + 75497472);

  cvt_f32_bf16_k<<<8192, 256, 0, stream>>>(x, xb, 2097152);
  cvt_transpose_k<<<12288, 256, 0, stream>>>(W_qkv, wqkvT, 3072);
  cvt_transpose_k<<<4096, 256, 0, stream>>>(W_out, woutT, 1024);

  dim3 g1(64, 24);
  gemm_bt<0><<<g1, 256, 0, stream>>>(xb, wqkvT, b_qkv, nullptr, q_ws, k_ws, vt_ws,
                                     8192, 3072, 1024);
  dim3 ga(16, 64);
  attn_k<<<ga, 256, 0, stream>>>(q_ws, k_ws, vt_ws, attb);

  dim3 g2(64, 8);
  gemm_bt<1><<<g2, 256, 0, stream>>>(attb, woutT, b_out, out, nullptr, nullptr, nullptr,
                                     8192, 1024, 1024);
}